// Round 3
// baseline (74.960 us; speedup 1.0000x reference)
//
#include <hip/hip_runtime.h>

#define P_POSES   32
#define A_ATOMS   4096
#define T_HASH    1048576
#define EPSF      1e-8f
#define ITEMS     2

typedef int int4v __attribute__((ext_vector_type(4)));

__global__ void zero_out_kernel(float* __restrict__ out) {
    int i = threadIdx.x;
    if (i < P_POSES) out[i] = 0.0f;
}

__global__ __launch_bounds__(256) void cartbonded_kernel(
    const float* __restrict__ coords,       // [P, A, 3]
    const float* __restrict__ hv,           // [T, 3]
    const int4v* __restrict__ atoms,        // [S, 4]
    const int*   __restrict__ pose,         // [S]
    const int*   __restrict__ uids,         // [P, A]
    float*       __restrict__ out,          // [P]
    int S, int NT)
{
    __shared__ float bins[P_POSES];
    if (threadIdx.x < P_POSES) bins[threadIdx.x] = 0.0f;
    __syncthreads();

    const int tid = blockIdx.x * blockDim.x + threadIdx.x;

    int   sIdx[ITEMS];
    bool  act[ITEMS];
    int4v a[ITEMS];
    int   p[ITEMS];

    #pragma unroll
    for (int j = 0; j < ITEMS; ++j) {
        sIdx[j] = tid + j * NT;
        act[j]  = sIdx[j] < S;
        if (act[j]) {
            a[j] = __builtin_nontemporal_load(&atoms[sIdx[j]]);
            p[j] = __builtin_nontemporal_load(&pose[sIdx[j]]);
        } else {
            a[j] = (int4v){0, 0, 0, 0};
            p[j] = 0;
        }
    }

    bool v0[ITEMS], v1[ITEMS], v2[ITEMS], v3[ITEMS];
    int  i0[ITEMS], i1[ITEMS], i2[ITEMS], i3[ITEMS];
    int  nv[ITEMS];
    unsigned int u0[ITEMS], u1[ITEMS], u2[ITEMS], u3[ITEMS];

    // Phase: issue all uid gathers (L2-resident, 512 KB table)
    #pragma unroll
    for (int j = 0; j < ITEMS; ++j) {
        v0[j] = a[j].x >= 0; v1[j] = a[j].y >= 0;
        v2[j] = a[j].z >= 0; v3[j] = a[j].w >= 0;
        i0[j] = v0[j] ? a[j].x : 0;
        i1[j] = v1[j] ? a[j].y : 0;
        i2[j] = v2[j] ? a[j].z : 0;
        i3[j] = v3[j] ? a[j].w : 0;
        nv[j] = (int)v0[j] + (int)v1[j] + (int)v2[j] + (int)v3[j];
        const int* __restrict__ urow = uids + p[j] * A_ATOMS;
        u0[j] = v0[j] ? (unsigned int)urow[i0[j]] : 0u;
        u1[j] = v1[j] ? (unsigned int)urow[i1[j]] : 0u;
        u2[j] = v2[j] ? (unsigned int)urow[i2[j]] : 0u;
        u3[j] = v3[j] ? (unsigned int)urow[i3[j]] : 0u;
    }

    // Phase: issue all coord gathers (L2-resident, 1.5 MB) — independent of uids
    float p0x[ITEMS], p0y[ITEMS], p0z[ITEMS];
    float p1x[ITEMS], p1y[ITEMS], p1z[ITEMS];
    float p2x[ITEMS], p2y[ITEMS], p2z[ITEMS];
    float p3x[ITEMS], p3y[ITEMS], p3z[ITEMS];
    #pragma unroll
    for (int j = 0; j < ITEMS; ++j) {
        const float* __restrict__ crow = coords + (size_t)p[j] * (A_ATOMS * 3);
        p0x[j] = crow[i0[j]*3+0]; p0y[j] = crow[i0[j]*3+1]; p0z[j] = crow[i0[j]*3+2];
        p1x[j] = crow[i1[j]*3+0]; p1y[j] = crow[i1[j]*3+1]; p1z[j] = crow[i1[j]*3+2];
        p2x[j] = crow[i2[j]*3+0]; p2y[j] = crow[i2[j]*3+1]; p2z[j] = crow[i2[j]*3+2];
        p3x[j] = crow[i3[j]*3+0]; p3y[j] = crow[i3[j]*3+1]; p3z[j] = crow[i3[j]*3+2];
    }

    // Phase: hash keys → issue hv gathers (the long-latency loads; overlap with math below)
    float K[ITEMS], x0[ITEMS], period[ITEMS];
    #pragma unroll
    for (int j = 0; j < ITEMS; ++j) {
        unsigned int key = (u0[j] + u1[j] + u2[j] + u3[j]) & (unsigned int)(T_HASH - 1);
        const float* __restrict__ hp = hv + (size_t)key * 3;
        K[j] = hp[0]; x0[j] = hp[1]; period[j] = hp[2];
    }

    // Phase: compute both items
    #pragma unroll
    for (int j = 0; j < ITEMS; ++j) {
        if (!act[j]) continue;

        // bond
        const float dbx = p1x[j]-p0x[j], dby = p1y[j]-p0y[j], dbz = p1z[j]-p0z[j];
        const float d  = sqrtf(dbx*dbx + dby*dby + dbz*dbz + EPSF);
        const float db = d - x0[j];
        const float e_bond = K[j] * db * db;

        // angle
        const float ux = p0x[j]-p1x[j], uy = p0y[j]-p1y[j], uz = p0z[j]-p1z[j];
        const float vx = p2x[j]-p1x[j], vy = p2y[j]-p1y[j], vz = p2z[j]-p1z[j];
        const float uv = ux*vx + uy*vy + uz*vz;
        const float uu = ux*ux + uy*uy + uz*uz;
        const float vv = vx*vx + vy*vy + vz*vz;
        float cosang = uv / (sqrtf(uu + EPSF) * sqrtf(vv + EPSF));
        cosang = fminf(fmaxf(cosang, -0.999999f), 0.999999f);
        const float theta = acosf(cosang);
        const float da = theta - x0[j];
        const float e_angle = K[j] * da * da;

        // torsion
        const float b1x = dbx, b1y = dby, b1z = dbz;
        const float b2x = p2x[j]-p1x[j], b2y = p2y[j]-p1y[j], b2z = p2z[j]-p1z[j];
        const float b3x = p3x[j]-p2x[j], b3y = p3y[j]-p2y[j], b3z = p3z[j]-p2z[j];
        const float n1x = b1y*b2z - b1z*b2y;
        const float n1y = b1z*b2x - b1x*b2z;
        const float n1z = b1x*b2y - b1y*b2x;
        const float n2x = b2y*b3z - b2z*b3y;
        const float n2y = b2z*b3x - b2x*b3z;
        const float n2z = b2x*b3y - b2y*b3x;
        const float b2inv = 1.0f / sqrtf(b2x*b2x + b2y*b2y + b2z*b2z + EPSF);
        const float bnx = b2x*b2inv, bny = b2y*b2inv, bnz = b2z*b2inv;
        const float m1x = n1y*bnz - n1z*bny;
        const float m1y = n1z*bnx - n1x*bnz;
        const float m1z = n1x*bny - n1y*bnx;
        const float sy = m1x*n2x + m1y*n2y + m1z*n2z;
        const float sx = n1x*n2x + n1y*n2y + n1z*n2z + EPSF;
        const float phi = atan2f(sy, sx);
        const float e_tors = K[j] * (1.0f + cosf(period[j]*phi - x0[j]));

        const float e = (nv[j] == 2) ? e_bond : ((nv[j] == 3) ? e_angle : e_tors);
        atomicAdd(&bins[p[j]], e);
    }

    __syncthreads();
    if (threadIdx.x < P_POSES) {
        const float b = bins[threadIdx.x];
        if (b != 0.0f) atomicAdd(&out[threadIdx.x], b);
    }
}

extern "C" void kernel_launch(void* const* d_in, const int* in_sizes, int n_in,
                              void* d_out, int out_size, void* d_ws, size_t ws_size,
                              hipStream_t stream) {
    const float* coords = (const float*)d_in[0];
    const float* hv     = (const float*)d_in[1];
    const int4v* atoms  = (const int4v*)d_in[2];
    const int*   pose   = (const int*)d_in[3];
    const int*   uids   = (const int*)d_in[4];
    float* out = (float*)d_out;

    const int S  = in_sizes[3];          // subgraph_pose element count
    const int NT = (S + ITEMS - 1) / ITEMS;

    zero_out_kernel<<<1, 64, 0, stream>>>(out);

    const int block = 256;
    const int grid  = (NT + block - 1) / block;
    cartbonded_kernel<<<grid, block, 0, stream>>>(coords, hv, atoms, pose, uids, out, S, NT);
}